// Round 1
// baseline (10020.269 us; speedup 1.0000x reference)
//
#include <hip/hip_runtime.h>
#include <math.h>

// Problem dims: M (math) is (r=8192, c=2048) = s^T. We store every big matrix
// TRANSPOSED, i.e. shape (2048, 8192) row-major, exactly like the input s.
#define RD 8192   // r (long dim, contiguous in storage)
#define CD 2048   // c (short dim, rows in storage)

// ============================================================================
// GEMM NT: Cp[z][i][j] = sum_{k in split z} A[i*K+k]*B[j*K+k]
// A,B row-major (rows x K). Used for: A = Mt*Sgt^T, B = Mt*Pt^T, S = Xt*Xt^T.
// 128x128 tile, BK=32, 256 threads, 8x8 microtile, split-K partials (no atomics).
// ============================================================================
__global__ __launch_bounds__(256) void gemm_nt_f32(
    const float* __restrict__ A, const float* __restrict__ B, float* __restrict__ Cp,
    int M, int N, int K, int ksplit)
{
  __shared__ float As[32][132];
  __shared__ float Bs[32][132];
  const int tid = threadIdx.x;
  const int tx = tid & 15, ty = tid >> 4;
  const int bi = blockIdx.y * 128, bj = blockIdx.x * 128;
  const int kchunk = K / ksplit;
  const int k0 = blockIdx.z * kchunk, k1 = k0 + kchunk;

  float acc[8][8];
#pragma unroll
  for (int i = 0; i < 8; ++i)
#pragma unroll
    for (int j = 0; j < 8; ++j) acc[i][j] = 0.f;

  const int lr = tid >> 3;        // 0..31
  const int lc = (tid & 7) * 4;   // 0,4,..,28

  for (int kt = k0; kt < k1; kt += 32) {
    __syncthreads();
#pragma unroll
    for (int q = 0; q < 4; ++q) {
      const int r = lr + q * 32;
      float4 av = *(const float4*)(A + (long)(bi + r) * K + kt + lc);
      As[lc + 0][r] = av.x; As[lc + 1][r] = av.y; As[lc + 2][r] = av.z; As[lc + 3][r] = av.w;
      float4 bv = *(const float4*)(B + (long)(bj + r) * K + kt + lc);
      Bs[lc + 0][r] = bv.x; Bs[lc + 1][r] = bv.y; Bs[lc + 2][r] = bv.z; Bs[lc + 3][r] = bv.w;
    }
    __syncthreads();
#pragma unroll 8
    for (int kk = 0; kk < 32; ++kk) {
      float a[8], b[8];
      *(float4*)(a)     = *(const float4*)&As[kk][ty * 8];
      *(float4*)(a + 4) = *(const float4*)&As[kk][ty * 8 + 4];
      *(float4*)(b)     = *(const float4*)&Bs[kk][tx * 8];
      *(float4*)(b + 4) = *(const float4*)&Bs[kk][tx * 8 + 4];
#pragma unroll
      for (int i = 0; i < 8; ++i)
#pragma unroll
        for (int j = 0; j < 8; ++j) acc[i][j] += a[i] * b[j];
    }
  }
  float* C = Cp + (long)blockIdx.z * M * N;
#pragma unroll
  for (int i = 0; i < 8; ++i) {
    const int r = bi + ty * 8 + i;
#pragma unroll
    for (int j = 0; j < 8; j += 4) {
      float4 v; v.x = acc[i][j]; v.y = acc[i][j + 1]; v.z = acc[i][j + 2]; v.w = acc[i][j + 3];
      *(float4*)(C + (long)r * N + bj + tx * 8 + j) = v;
    }
  }
}

// ============================================================================
// GEMM NN with fused epilogue:
//   C[i][j] = beta*D[i][j] + gamma*E[i][j] + sgn * sum_k A[i*K+k]*B[k*N+j]
// Used for: Gt = 0.1*Sgt - Asym*Mt   and   Xt = Mt - Pt + Bsym*Mt  (in-place ok:
// E is read exactly once by the owning thread before C is written).
// ============================================================================
__global__ __launch_bounds__(256) void gemm_nn_f32(
    const float* __restrict__ A, const float* __restrict__ B,
    const float* __restrict__ D, const float* __restrict__ E, float* __restrict__ C,
    int M, int N, int K, float beta, float gamma, float sgn)
{
  __shared__ float As[32][132];
  __shared__ float Bs[32][132];
  const int tid = threadIdx.x;
  const int tx = tid & 15, ty = tid >> 4;
  const int bi = blockIdx.y * 128, bj = blockIdx.x * 128;

  float acc[8][8];
#pragma unroll
  for (int i = 0; i < 8; ++i)
#pragma unroll
    for (int j = 0; j < 8; ++j) acc[i][j] = 0.f;

  const int lr = tid >> 3, lc = (tid & 7) * 4;    // A tile: 128 rows x 32 k
  const int kr = tid >> 5, kc = (tid & 31) * 4;   // B tile: 32 k x 128 cols

  for (int kt = 0; kt < K; kt += 32) {
    __syncthreads();
#pragma unroll
    for (int q = 0; q < 4; ++q) {
      const int r = lr + q * 32;
      float4 av = *(const float4*)(A + (long)(bi + r) * K + kt + lc);
      As[lc + 0][r] = av.x; As[lc + 1][r] = av.y; As[lc + 2][r] = av.z; As[lc + 3][r] = av.w;
      const int kb2 = kr + q * 8;
      float4 bv = *(const float4*)(B + (long)(kt + kb2) * N + bj + kc);
      *(float4*)&Bs[kb2][kc] = bv;
    }
    __syncthreads();
#pragma unroll 8
    for (int kk = 0; kk < 32; ++kk) {
      float a[8], b[8];
      *(float4*)(a)     = *(const float4*)&As[kk][ty * 8];
      *(float4*)(a + 4) = *(const float4*)&As[kk][ty * 8 + 4];
      *(float4*)(b)     = *(const float4*)&Bs[kk][tx * 8];
      *(float4*)(b + 4) = *(const float4*)&Bs[kk][tx * 8 + 4];
#pragma unroll
      for (int i = 0; i < 8; ++i)
#pragma unroll
        for (int j = 0; j < 8; ++j) acc[i][j] += a[i] * b[j];
    }
  }
#pragma unroll
  for (int i = 0; i < 8; ++i) {
    const int r = bi + ty * 8 + i;
#pragma unroll
    for (int j = 0; j < 8; j += 4) {
      const long off = (long)r * N + bj + tx * 8 + j;
      float4 v;
      v.x = sgn * acc[i][j];     v.y = sgn * acc[i][j + 1];
      v.z = sgn * acc[i][j + 2]; v.w = sgn * acc[i][j + 3];
      if (D) { float4 d = *(const float4*)(D + off); v.x += beta * d.x; v.y += beta * d.y; v.z += beta * d.z; v.w += beta * d.w; }
      if (E) { float4 e = *(const float4*)(E + off); v.x += gamma * e.x; v.y += gamma * e.y; v.z += gamma * e.z; v.w += gamma * e.w; }
      *(float4*)(C + off) = v;
    }
  }
}

// ============================================================================
// sym_combine: out[i][j] = scale * sum_s (Cp[s][i][j] + Cp[s][j][i]), n x n.
// Transposed tile staged via LDS for coalesced reads. Also serves as the plain
// split-K reducer for the (numerically symmetric) Gram partials.
// ============================================================================
__global__ __launch_bounds__(256) void sym_combine(
    const float* __restrict__ Cp, float* __restrict__ out, int n, int nsplit, float scale)
{
  __shared__ float Ts[64][68];
  const int tid = threadIdx.x;
  const int tx = tid & 15, ty = tid >> 4;
  const int bi = blockIdx.y * 64, bj = blockIdx.x * 64;
  float acc[4][4];
#pragma unroll
  for (int i = 0; i < 4; ++i)
#pragma unroll
    for (int j = 0; j < 4; ++j) acc[i][j] = 0.f;

  for (int s = 0; s < nsplit; ++s) {
    const float* C = Cp + (long)s * n * n;
#pragma unroll
    for (int i = 0; i < 4; ++i) {
      float4 v = *(const float4*)(C + (long)(bi + ty * 4 + i) * n + bj + tx * 4);
      acc[i][0] += v.x; acc[i][1] += v.y; acc[i][2] += v.z; acc[i][3] += v.w;
    }
    __syncthreads();
#pragma unroll
    for (int i = 0; i < 4; ++i) {
      float4 w = *(const float4*)(C + (long)(bj + ty * 4 + i) * n + bi + tx * 4);
      *(float4*)&Ts[ty * 4 + i][tx * 4] = w;
    }
    __syncthreads();
#pragma unroll
    for (int i = 0; i < 4; ++i)
#pragma unroll
      for (int j = 0; j < 4; ++j) acc[i][j] += Ts[tx * 4 + j][ty * 4 + i];
  }
#pragma unroll
  for (int i = 0; i < 4; ++i) {
    float4 v; v.x = scale * acc[i][0]; v.y = scale * acc[i][1]; v.z = scale * acc[i][2]; v.w = scale * acc[i][3];
    *(float4*)(out + (long)(bi + ty * 4 + i) * n + bj + tx * 4) = v;
  }
}

// ============================================================================
// Reductions for the LSTM diag inputs.
// gtg[row] = sum_j G[row][j]^2 / RD   (one block per row)
// ggt[col] += partial sum_i G[i][col]^2 / CD   (atomics; pre-zeroed)
// ============================================================================
__global__ __launch_bounds__(256) void row_sumsq(const float* __restrict__ G, float* __restrict__ out, float inv)
{
  __shared__ float red[256];
  const int tid = threadIdx.x;
  const float4* row = (const float4*)(G + (long)blockIdx.x * RD);
  float s = 0.f;
  for (int c = tid; c < RD / 4; c += 256) {
    float4 v = row[c];
    s += v.x * v.x + v.y * v.y + v.z * v.z + v.w * v.w;
  }
  red[tid] = s; __syncthreads();
  for (int off = 128; off > 0; off >>= 1) { if (tid < off) red[tid] += red[tid + off]; __syncthreads(); }
  if (tid == 0) out[blockIdx.x] = red[0] * inv;
}

__global__ __launch_bounds__(256) void col_sumsq(const float* __restrict__ G, float* __restrict__ out)
{
  const int rr = blockIdx.x * 256 + threadIdx.x;
  const int cc0 = blockIdx.y * 256;
  float s = 0.f;
  for (int i = 0; i < 256; ++i) {
    float v = G[(long)(cc0 + i) * RD + rr];
    s += v * v;
  }
  atomicAdd(&out[rr], s * (1.f / (float)CD));
}

// ============================================================================
// 2-layer LSTM single step + linear head. One thread per batch row.
// x = clip(log(|diag|)/10, -1, 1). Gate order i,f,g,o. Also accumulates
// sum(l_pre) for the mean (block-reduced, one atomic per block; pre-zeroed).
// ============================================================================
__device__ __forceinline__ float sigm_(float x) { return 1.f / (1.f + __expf(-x)); }
__device__ __forceinline__ float tanh_(float x) { float e = __expf(2.f * x); return 1.f - 2.f / (e + 1.f); }

__global__ __launch_bounds__(256) void lstm_head(
    const float* __restrict__ diag, int B,
    const float* __restrict__ h0, const float* __restrict__ c0,
    const float* __restrict__ Wih0, const float* __restrict__ Whh0,
    const float* __restrict__ bih0, const float* __restrict__ bhh0,
    const float* __restrict__ Wih1, const float* __restrict__ Whh1,
    const float* __restrict__ bih1, const float* __restrict__ bhh1,
    const float* __restrict__ HW, const float* __restrict__ Hb,
    float* __restrict__ pre, float* __restrict__ sum_out)
{
  __shared__ float w0[80], wh0[1600], b0[80], wi1[1600], wh1[1600], b1[80], hw[20];
  __shared__ float red[256];
  const int tid = threadIdx.x;
  for (int i = tid; i < 80; i += 256) { w0[i] = Wih0[i]; b0[i] = bih0[i] + bhh0[i]; b1[i] = bih1[i] + bhh1[i]; }
  for (int i = tid; i < 1600; i += 256) { wh0[i] = Whh0[i]; wi1[i] = Wih1[i]; wh1[i] = Whh1[i]; }
  if (tid < 20) hw[tid] = HW[tid];
  __syncthreads();

  const int b = blockIdx.x * 256 + tid;
  const float d = diag[b];
  float x = logf(fabsf(d)) * 0.1f;            // /P_CLAMP ; log(0)=-inf clamps to -1
  x = fminf(fmaxf(x, -1.f), 1.f);

  const float* h0p = h0 + (long)b * 20;
  const float* c0p = c0 + (long)b * 20;
  const float* h1p = h0 + (long)B * 20 + (long)b * 20;
  const float* c1p = c0 + (long)B * 20 + (long)b * 20;

  float h0r[20], hA[20];
#pragma unroll
  for (int m = 0; m < 20; ++m) h0r[m] = h0p[m];
#pragma unroll
  for (int h = 0; h < 20; ++h) {
    float gi = w0[h] * x + b0[h];
    float gf = w0[20 + h] * x + b0[20 + h];
    float gg = w0[40 + h] * x + b0[40 + h];
    float go = w0[60 + h] * x + b0[60 + h];
#pragma unroll
    for (int m = 0; m < 20; ++m) {
      const float hm = h0r[m];
      gi += wh0[h * 20 + m] * hm;
      gf += wh0[(20 + h) * 20 + m] * hm;
      gg += wh0[(40 + h) * 20 + m] * hm;
      go += wh0[(60 + h) * 20 + m] * hm;
    }
    const float cc = sigm_(gf) * c0p[h] + sigm_(gi) * tanh_(gg);
    hA[h] = sigm_(go) * tanh_(cc);
  }
  float h1r[20];
#pragma unroll
  for (int m = 0; m < 20; ++m) h1r[m] = h1p[m];
  float pr = 0.f;
#pragma unroll
  for (int h = 0; h < 20; ++h) {
    float gi = b1[h], gf = b1[20 + h], gg = b1[40 + h], go = b1[60 + h];
#pragma unroll
    for (int m = 0; m < 20; ++m) {
      const float am = hA[m], hm = h1r[m];
      gi += wi1[h * 20 + m] * am + wh1[h * 20 + m] * hm;
      gf += wi1[(20 + h) * 20 + m] * am + wh1[(20 + h) * 20 + m] * hm;
      gg += wi1[(40 + h) * 20 + m] * am + wh1[(40 + h) * 20 + m] * hm;
      go += wi1[(60 + h) * 20 + m] * am + wh1[(60 + h) * 20 + m] * hm;
    }
    const float cc = sigm_(gf) * c1p[h] + sigm_(gi) * tanh_(gg);
    pr += sigm_(go) * tanh_(cc) * hw[h];
  }
  pr = (pr + Hb[0]) * 0.1f;   // OUTPUT_SCALE
  pre[b] = pr;

  red[tid] = pr; __syncthreads();
  for (int off = 128; off > 0; off >>= 1) { if (tid < off) red[tid] += red[tid + off]; __syncthreads(); }
  if (tid == 0) atomicAdd(sum_out, red[0]);
}

// ============================================================================
// Pt[cc][rr] = Rv(cc) * Gt[cc][rr] * Lv(rr), in place.
// Lv/Rv = max(pre - mean + 1, before).
// ============================================================================
__global__ __launch_bounds__(256) void scale_P(
    float* __restrict__ G, const float* __restrict__ lpre, const float* __restrict__ rpre,
    const float* __restrict__ Lbef, const float* __restrict__ Rbef, const float* __restrict__ sums)
{
  const long id4 = ((long)blockIdx.x * 256 + threadIdx.x) * 4;
  const int cc = (int)(id4 >> 13);
  const int rr = (int)(id4 & (RD - 1));
  const float meanl = sums[0] * (1.f / (float)RD);
  const float meanr = sums[1] * (1.f / (float)CD);
  const float rv = fmaxf(rpre[cc] - meanr + 1.f, Rbef[cc]);
  float4 g  = *(float4*)(G + id4);
  float4 lp = *(const float4*)(lpre + rr);
  float4 lb = *(const float4*)(Lbef + rr);
  g.x *= rv * fmaxf(lp.x - meanl + 1.f, lb.x);
  g.y *= rv * fmaxf(lp.y - meanl + 1.f, lb.y);
  g.z *= rv * fmaxf(lp.z - meanl + 1.f, lb.z);
  g.w *= rv * fmaxf(lp.w - meanl + 1.f, lb.w);
  *(float4*)(G + id4) = g;
}

// ============================================================================
// Blocked Cholesky (NB=64) of S (2048x2048, lower), L written back into S.
// potrf64 also produces inv(L_kk) (64x64, zeros in upper) into invD[kb].
// ============================================================================
__global__ __launch_bounds__(256) void potrf64(float* __restrict__ S, float* __restrict__ invD, int kb)
{
  __shared__ float Ls[64][65];
  __shared__ float Ws[64][65];
  const int tid = threadIdx.x;
  const int tx = tid & 15, ty = tid >> 4;
  const long o = (long)kb * 64;

  for (int t = tid; t < 4096; t += 256) { int r = t >> 6, c = t & 63; Ls[r][c] = S[(o + r) * CD + o + c]; }
  __syncthreads();

  for (int j = 0; j < 64; ++j) {
    const float dj = Ls[j][j];          // all threads read (post-sync)
    const float sd = sqrtf(dj);
    const float rd = 1.f / sd;
    __syncthreads();                    // reads done before column write
    for (int i = j + tid; i < 64; i += 256) Ls[i][j] *= rd;   // i==j -> sd
    __syncthreads();
    for (int i = j + 1 + ty; i < 64; i += 16) {
      const float lij = Ls[i][j];
      for (int c = j + 1 + tx; c < 64; c += 16) Ls[i][c] -= lij * Ls[c][j];
    }
    __syncthreads();
  }

  // inv(L) by forward substitution, one thread per column
  if (tid < 64) {
    const int c = tid;
    for (int i = 0; i < c; ++i) Ws[i][c] = 0.f;
    Ws[c][c] = 1.f / Ls[c][c];
    for (int i = c + 1; i < 64; ++i) {
      float s = 0.f;
      for (int m = c; m < i; ++m) s += Ls[i][m] * Ws[m][c];
      Ws[i][c] = -s / Ls[i][i];
    }
  }
  __syncthreads();

  for (int t = tid; t < 4096; t += 256) {
    int r = t >> 6, c = t & 63;
    if (c <= r) S[(o + r) * CD + o + c] = Ls[r][c];
    invD[(long)kb * 4096 + t] = Ws[r][c];
  }
}

// Panel: S(ib,kb) <- S(ib,kb) * inv(L_kk)^T
__global__ __launch_bounds__(256) void panel64(float* __restrict__ S, const float* __restrict__ invD, int kb)
{
  __shared__ float Ss[64][65];
  __shared__ float Ws[64][65];
  const int tid = threadIdx.x, tx = tid & 15, ty = tid >> 4;
  const int ib = kb + 1 + blockIdx.x;
  const long ro = (long)ib * 64, co = (long)kb * 64;
  for (int t = tid; t < 4096; t += 256) {
    int r = t >> 6, c = t & 63;
    Ss[r][c] = S[(ro + r) * CD + co + c];
    Ws[r][c] = invD[(long)kb * 4096 + t];
  }
  __syncthreads();
  float acc[4][4];
#pragma unroll
  for (int i = 0; i < 4; ++i)
#pragma unroll
    for (int j = 0; j < 4; ++j) acc[i][j] = 0.f;
#pragma unroll 4
  for (int m = 0; m < 64; ++m) {
    float a[4], w[4];
#pragma unroll
    for (int i = 0; i < 4; ++i) { a[i] = Ss[ty * 4 + i][m]; w[i] = Ws[tx * 4 + i][m]; }
#pragma unroll
    for (int i = 0; i < 4; ++i)
#pragma unroll
      for (int j = 0; j < 4; ++j) acc[i][j] += a[i] * w[j];
  }
#pragma unroll
  for (int i = 0; i < 4; ++i)
#pragma unroll
    for (int j = 0; j < 4; ++j)
      S[(ro + ty * 4 + i) * CD + co + tx * 4 + j] = acc[i][j];
}

// Trailing: S(ib,jb) -= L(ib,kb) * L(jb,kb)^T   (lower tiles only)
__global__ __launch_bounds__(256) void trail64(float* __restrict__ S, int kb)
{
  const int jb = kb + 1 + blockIdx.x, ib = kb + 1 + blockIdx.y;
  if (jb > ib) return;
  __shared__ float Li[64][65];
  __shared__ float Lj[64][65];
  const int tid = threadIdx.x, tx = tid & 15, ty = tid >> 4;
  const long io = (long)ib * 64, jo = (long)jb * 64, ko = (long)kb * 64;
  for (int t = tid; t < 4096; t += 256) {
    int r = t >> 6, c = t & 63;
    Li[r][c] = S[(io + r) * CD + ko + c];
    Lj[r][c] = S[(jo + r) * CD + ko + c];
  }
  __syncthreads();
  float acc[4][4];
#pragma unroll
  for (int i = 0; i < 4; ++i)
#pragma unroll
    for (int j = 0; j < 4; ++j) acc[i][j] = 0.f;
#pragma unroll 4
  for (int m = 0; m < 64; ++m) {
    float a[4], w[4];
#pragma unroll
    for (int i = 0; i < 4; ++i) { a[i] = Li[ty * 4 + i][m]; w[i] = Lj[tx * 4 + i][m]; }
#pragma unroll
    for (int i = 0; i < 4; ++i)
#pragma unroll
      for (int j = 0; j < 4; ++j) acc[i][j] += a[i] * w[j];
  }
#pragma unroll
  for (int i = 0; i < 4; ++i)
#pragma unroll
    for (int j = 0; j < 4; ++j) {
      const long off = (io + ty * 4 + i) * CD + jo + tx * 4 + j;
      S[off] -= acc[i][j];
    }
}

// ============================================================================
// Blocked forward solve: L * Qt = Xt, one 64-row block per step.
// Qt(ib) = invL_ii * (Xt(ib) - sum_{jb<ib} L(ib,jb) * Qt(jb)).  Qt == d_out.
// ============================================================================
__global__ __launch_bounds__(256) void solve64(
    const float* __restrict__ S, const float* __restrict__ invD,
    const float* __restrict__ X, float* __restrict__ Q, int ib)
{
  __shared__ float Lb[64][65];
  __shared__ float Qb[64][68];
  const int tid = threadIdx.x, tx = tid & 15, ty = tid >> 4;
  const int c0 = blockIdx.x * 64;
  const long r0 = (long)ib * 64;

  float acc[4][4];
#pragma unroll
  for (int i = 0; i < 4; ++i) {
    float4 v = *(const float4*)(X + (r0 + ty * 4 + i) * RD + c0 + tx * 4);
    acc[i][0] = v.x; acc[i][1] = v.y; acc[i][2] = v.z; acc[i][3] = v.w;
  }
  for (int jb = 0; jb < ib; ++jb) {
    __syncthreads();
    for (int t = tid; t < 4096; t += 256) {
      int r = t >> 6, c = t & 63;
      Lb[r][c] = S[(r0 + r) * CD + (long)jb * 64 + c];
      Qb[r][c] = Q[((long)jb * 64 + r) * RD + c0 + c];
    }
    __syncthreads();
#pragma unroll 4
    for (int m = 0; m < 64; ++m) {
      float l[4], q[4];
#pragma unroll
      for (int i = 0; i < 4; ++i) { l[i] = Lb[ty * 4 + i][m]; q[i] = Qb[m][tx * 4 + i]; }
#pragma unroll
      for (int i = 0; i < 4; ++i)
#pragma unroll
        for (int j = 0; j < 4; ++j) acc[i][j] -= l[i] * q[j];
    }
  }
  __syncthreads();
#pragma unroll
  for (int i = 0; i < 4; ++i) {
    float4 v; v.x = acc[i][0]; v.y = acc[i][1]; v.z = acc[i][2]; v.w = acc[i][3];
    *(float4*)&Qb[ty * 4 + i][tx * 4] = v;
  }
  for (int t = tid; t < 4096; t += 256) Lb[t >> 6][t & 63] = invD[(long)ib * 4096 + t];
  __syncthreads();

  float o_[4][4];
#pragma unroll
  for (int i = 0; i < 4; ++i)
#pragma unroll
    for (int j = 0; j < 4; ++j) o_[i][j] = 0.f;
#pragma unroll 4
  for (int m = 0; m < 64; ++m) {
    float l[4], q[4];
#pragma unroll
    for (int i = 0; i < 4; ++i) { l[i] = Lb[ty * 4 + i][m]; q[i] = Qb[m][tx * 4 + i]; }
#pragma unroll
    for (int i = 0; i < 4; ++i)
#pragma unroll
      for (int j = 0; j < 4; ++j) o_[i][j] += l[i] * q[j];
  }
#pragma unroll
  for (int i = 0; i < 4; ++i) {
    float4 v; v.x = o_[i][0]; v.y = o_[i][1]; v.z = o_[i][2]; v.w = o_[i][3];
    *(float4*)(Q + (r0 + ty * 4 + i) * RD + c0 + tx * 4) = v;
  }
}

// ============================================================================
// Host launch. All math matrices stored transposed ((2048,8192) row-major):
//   Mt = s, Mgt = 0.1*s_grad (folded), Gt/Pt/Xt share one 64 MB buffer,
//   NT split-K partials live in d_out (overwritten later by Q).
// ============================================================================
extern "C" void kernel_launch(void* const* d_in, const int* in_sizes, int n_in,
                              void* d_out, int out_size, void* d_ws, size_t ws_size,
                              hipStream_t stream)
{
  const float* s_in  = (const float*)d_in[0];
  const float* sgrad = (const float*)d_in[1];
  const float* L_h0  = (const float*)d_in[2];
  const float* L_c0  = (const float*)d_in[3];
  const float* R_h0  = (const float*)d_in[4];
  const float* R_c0  = (const float*)d_in[5];
  const float* L_bef = (const float*)d_in[6];
  const float* R_bef = (const float*)d_in[7];
  const float* Wih0  = (const float*)d_in[8];
  const float* Whh0  = (const float*)d_in[9];
  const float* bih0  = (const float*)d_in[10];
  const float* bhh0  = (const float*)d_in[11];
  const float* Wih1  = (const float*)d_in[12];
  const float* Whh1  = (const float*)d_in[13];
  const float* bih1  = (const float*)d_in[14];
  const float* bhh1  = (const float*)d_in[15];
  const float* L_W   = (const float*)d_in[16];
  const float* L_b   = (const float*)d_in[17];
  const float* R_W   = (const float*)d_in[18];
  const float* R_b   = (const float*)d_in[19];

  float* out = (float*)d_out;
  char*  ws  = (char*)d_ws;

  const size_t SYM_OFF = (size_t)1 << 17;                       // 128 KB for vectors
  const size_t INV_OFF = SYM_OFF + ((size_t)16 << 20);          // +16 MB sym matrix
  const size_t BIG_OFF = INV_OFF + ((size_t)1 << 20);           // +1 MB invD
  float* vec  = (float*)ws;
  float* sums = vec;                  // [0]=sum_l, [1]=sum_r
  float* ggt  = vec + 4;              // 8192
  float* gtg  = ggt + RD;             // 2048
  float* lpre = gtg + CD;             // 8192
  float* rpre = lpre + RD;            // 2048
  float* SYM  = (float*)(ws + SYM_OFF);   // Asym -> Bsym -> S/L
  float* invD = (float*)(ws + INV_OFF);   // 32 x 64x64 inverse diag blocks
  float* BIG  = (float*)(ws + BIG_OFF);   // Gt -> Pt -> Xt (in place)
  float* Cp   = out;                      // NT split-K partials (4 x 2048^2)

  hipMemsetAsync(vec, 0, (4 + RD) * sizeof(float), stream);     // sums + ggt (atomics)

  const dim3 blk(256);
  const dim3 gNT(16, 16, 4);   // 2048/128 x 2048/128 x splitK
  const dim3 gNN(64, 16);      // 8192/128 x 2048/128
  const dim3 gSym(32, 32);     // 2048/64 x 2048/64

  // --- G = orth_proj(M, 0.1*M_grad) ---
  gemm_nt_f32<<<gNT, blk, 0, stream>>>(s_in, sgrad, Cp, CD, CD, RD, 4);
  sym_combine<<<gSym, blk, 0, stream>>>(Cp, SYM, CD, 4, 0.05f);               // 0.5 * s_lr
  gemm_nn_f32<<<gNN, blk, 0, stream>>>(SYM, s_in, sgrad, nullptr, BIG,
                                       CD, RD, CD, 0.1f, 0.f, -1.f);          // Gt

  // --- diag(G G^T)/c , diag(G^T G)/r ---
  row_sumsq<<<CD, blk, 0, stream>>>(BIG, gtg, 1.f / (float)RD);
  col_sumsq<<<dim3(RD / 256, CD / 256), blk, 0, stream>>>(BIG, ggt);

  // --- LSTM heads ---
  lstm_head<<<RD / 256, blk, 0, stream>>>(ggt, RD, L_h0, L_c0, Wih0, Whh0, bih0, bhh0,
                                          Wih1, Whh1, bih1, bhh1, L_W, L_b, lpre, &sums[0]);
  lstm_head<<<CD / 256, blk, 0, stream>>>(gtg, CD, R_h0, R_c0, Wih0, Whh0, bih0, bhh0,
                                          Wih1, Whh1, bih1, bhh1, R_W, R_b, rpre, &sums[1]);

  // --- P = Lv * G * Rv (in place) ---
  scale_P<<<(CD * (RD / 4)) / 256, blk, 0, stream>>>(BIG, lpre, rpre, L_bef, R_bef, sums);

  // --- X = M - orth_proj(M, P) = M - P + M*Bsym ---
  gemm_nt_f32<<<gNT, blk, 0, stream>>>(s_in, BIG, Cp, CD, CD, RD, 4);
  sym_combine<<<gSym, blk, 0, stream>>>(Cp, SYM, CD, 4, 0.5f);                // Bsym
  gemm_nn_f32<<<gNN, blk, 0, stream>>>(SYM, s_in, s_in, BIG, BIG,
                                       CD, RD, CD, 1.f, -1.f, 1.f);           // Xt (in place)

  // --- CholeskyQR: S = X^T X ; S = L L^T ; solve L Qt = Xt ---
  gemm_nt_f32<<<gNT, blk, 0, stream>>>(BIG, BIG, Cp, CD, CD, RD, 4);
  sym_combine<<<gSym, blk, 0, stream>>>(Cp, SYM, CD, 4, 0.5f);                // Gram S

  for (int kb = 0; kb < 32; ++kb) {
    potrf64<<<1, blk, 0, stream>>>(SYM, invD, kb);
    const int nrem = 31 - kb;
    if (nrem > 0) {
      panel64<<<nrem, blk, 0, stream>>>(SYM, invD, kb);
      trail64<<<dim3(nrem, nrem), blk, 0, stream>>>(SYM, kb);
    }
  }
  for (int ib = 0; ib < 32; ++ib)
    solve64<<<RD / 64, blk, 0, stream>>>(SYM, invD, BIG, out, ib);
}

// Round 2
// 6157.658 us; speedup vs baseline: 1.6273x; 1.6273x over previous
//
#include <hip/hip_runtime.h>
#include <math.h>

#define RD 8192   // r (long dim, contiguous in storage)
#define CD 2048   // c (short dim, rows in storage)

typedef _Float16 f16x8 __attribute__((ext_vector_type(8)));
typedef _Float16 f16x4 __attribute__((ext_vector_type(4)));
typedef float    f32x4 __attribute__((ext_vector_type(4)));

#define GLOBAL_AS __attribute__((address_space(1)))
#define LDS_AS    __attribute__((address_space(3)))

// ============================================================================
// f16 MFMA GEMM (NT): C[i][j] = sum_k A[i*K+k] * B[j*K+k], fp32 accumulate.
// 128x128 tile, BK=32, 256 thr = 4 waves (2x2), 4x4 x (16x16x32) MFMA per wave.
// Staging via global_load_lds width=16 (m97 structure).
// mode A (Cp != 0): write fp32 partials Cp[z][i][j]  (split-K via blockIdx.z)
// mode B (Cp == 0): Of16[i][j] = f16( sgn*acc + beta*Dg[ij] + gamma*Eg[ij] )
// ============================================================================
__global__ __launch_bounds__(256) void gemm_nt_f16(
    const _Float16* __restrict__ A, const _Float16* __restrict__ B,
    float* __restrict__ Cp, _Float16* __restrict__ Of16,
    const float* __restrict__ Dg, const _Float16* __restrict__ Eg,
    int M, int N, int K, int ksplit, float beta, float gamma, float sgn)
{
  __shared__ __align__(1024) _Float16 As[128 * 32];
  __shared__ __align__(1024) _Float16 Bs[128 * 32];
  const int tid = threadIdx.x;
  const int wave = tid >> 6, lane = tid & 63;
  const int wy = wave >> 1, wx = wave & 1;
  const int bi = blockIdx.y * 128, bj = blockIdx.x * 128;
  const int kchunk = K / ksplit;
  const long k0 = (long)blockIdx.z * kchunk;

  f32x4 acc[4][4];
#pragma unroll
  for (int i = 0; i < 4; ++i)
#pragma unroll
    for (int j = 0; j < 4; ++j) acc[i][j] = (f32x4){0.f, 0.f, 0.f, 0.f};

  // staging: per wave, 2 issues of 16 rows for A and B; lane -> (row, 16B seg)
  const int srow = wave * 16 + (lane >> 2);
  const int skof = (lane & 3) * 8;
  const _Float16* aA = A + (long)(bi + srow) * K + k0 + skof;
  const _Float16* aB = B + (long)(bj + srow) * K + k0 + skof;
  _Float16* lA = As + wave * 16 * 32;
  _Float16* lB = Bs + wave * 16 * 32;

  const int fr = lane & 15;           // row within 16-tile
  const int fk = (lane >> 4) * 8;     // k offset within BK

  for (int kt = 0; kt < kchunk; kt += 32) {
    __syncthreads();
#pragma unroll
    for (int q = 0; q < 2; ++q) {
      __builtin_amdgcn_global_load_lds(
          (const GLOBAL_AS unsigned int*)(aA + (long)q * 64 * K + kt),
          (LDS_AS unsigned int*)(lA + q * 64 * 32), 16, 0, 0);
      __builtin_amdgcn_global_load_lds(
          (const GLOBAL_AS unsigned int*)(aB + (long)q * 64 * K + kt),
          (LDS_AS unsigned int*)(lB + q * 64 * 32), 16, 0, 0);
    }
    __syncthreads();   // compiler drains vmcnt before s_barrier

    f16x8 af[4], bf[4];
#pragma unroll
    for (int t = 0; t < 4; ++t) {
      af[t] = *(const f16x8*)(As + (wy * 64 + t * 16 + fr) * 32 + fk);
      bf[t] = *(const f16x8*)(Bs + (wx * 64 + t * 16 + fr) * 32 + fk);
    }
#pragma unroll
    for (int mt = 0; mt < 4; ++mt)
#pragma unroll
      for (int nt = 0; nt < 4; ++nt)
        acc[mt][nt] = __builtin_amdgcn_mfma_f32_16x16x32_f16(af[mt], bf[nt], acc[mt][nt], 0, 0, 0);
  }

  // C/D layout: col = lane&15, row = (lane>>4)*4 + reg
  const int quad = lane >> 4, fc = lane & 15;
  if (Cp) {
    float* Cz = Cp + (long)blockIdx.z * M * N;
#pragma unroll
    for (int mt = 0; mt < 4; ++mt)
#pragma unroll
      for (int nt = 0; nt < 4; ++nt) {
        const int col = bj + wx * 64 + nt * 16 + fc;
#pragma unroll
        for (int reg = 0; reg < 4; ++reg) {
          const int row = bi + wy * 64 + mt * 16 + quad * 4 + reg;
          Cz[(long)row * N + col] = acc[mt][nt][reg];
        }
      }
  } else {
#pragma unroll
    for (int mt = 0; mt < 4; ++mt)
#pragma unroll
      for (int nt = 0; nt < 4; ++nt) {
        const int col = bj + wx * 64 + nt * 16 + fc;
#pragma unroll
        for (int reg = 0; reg < 4; ++reg) {
          const int row = bi + wy * 64 + mt * 16 + quad * 4 + reg;
          const long off = (long)row * N + col;
          float v = sgn * acc[mt][nt][reg];
          if (Dg) v += beta * Dg[off];
          if (Eg) v += gamma * (float)Eg[off];
          Of16[off] = (_Float16)v;
        }
      }
  }
}

// ============================================================================
// sym_combine: out[i][j] = scale * sum_z (Cp[z][i][j] + Cp[z][j][i]), n x n fp32.
// ============================================================================
__global__ __launch_bounds__(256) void sym_combine(
    const float* __restrict__ Cp, float* __restrict__ out, int n, int nsplit, float scale)
{
  __shared__ float Ts[64][68];
  const int tid = threadIdx.x;
  const int tx = tid & 15, ty = tid >> 4;
  const int bi = blockIdx.y * 64, bj = blockIdx.x * 64;
  float acc[4][4];
#pragma unroll
  for (int i = 0; i < 4; ++i)
#pragma unroll
    for (int j = 0; j < 4; ++j) acc[i][j] = 0.f;

  for (int s = 0; s < nsplit; ++s) {
    const float* C = Cp + (long)s * n * n;
#pragma unroll
    for (int i = 0; i < 4; ++i) {
      float4 v = *(const float4*)(C + (long)(bi + ty * 4 + i) * n + bj + tx * 4);
      acc[i][0] += v.x; acc[i][1] += v.y; acc[i][2] += v.z; acc[i][3] += v.w;
    }
    __syncthreads();
#pragma unroll
    for (int i = 0; i < 4; ++i) {
      float4 w = *(const float4*)(C + (long)(bj + ty * 4 + i) * n + bi + tx * 4);
      *(float4*)&Ts[ty * 4 + i][tx * 4] = w;
    }
    __syncthreads();
#pragma unroll
    for (int i = 0; i < 4; ++i)
#pragma unroll
      for (int j = 0; j < 4; ++j) acc[i][j] += Ts[tx * 4 + j][ty * 4 + i];
  }
#pragma unroll
  for (int i = 0; i < 4; ++i) {
    float4 v; v.x = scale * acc[i][0]; v.y = scale * acc[i][1]; v.z = scale * acc[i][2]; v.w = scale * acc[i][3];
    *(float4*)(out + (long)(bi + ty * 4 + i) * n + bj + tx * 4) = v;
  }
}

// ============================================================================
// Casts: fp32 -> f16 flat; fp32 (CD x RD) -> transposed f16 (RD x CD).
// ============================================================================
__global__ __launch_bounds__(256) void cast_f16(const float* __restrict__ s, _Float16* __restrict__ d)
{
  const long i = ((long)blockIdx.x * 256 + threadIdx.x) * 4;
  float4 v = *(const float4*)(s + i);
  f16x4 o; o[0] = (_Float16)v.x; o[1] = (_Float16)v.y; o[2] = (_Float16)v.z; o[3] = (_Float16)v.w;
  *(f16x4*)(d + i) = o;
}

__global__ __launch_bounds__(256) void transpose_cast_f16(
    const float* __restrict__ src, _Float16* __restrict__ dst)
{
  __shared__ float T[64][65];
  const int tid = threadIdx.x, tx = tid & 15, ty = tid >> 4;
  const int r0 = blockIdx.x * 64, c0 = blockIdx.y * 64;
#pragma unroll
  for (int i = 0; i < 4; ++i) {
    float4 v = *(const float4*)(src + (long)(c0 + ty * 4 + i) * RD + r0 + tx * 4);
    T[ty * 4 + i][tx * 4 + 0] = v.x; T[ty * 4 + i][tx * 4 + 1] = v.y;
    T[ty * 4 + i][tx * 4 + 2] = v.z; T[ty * 4 + i][tx * 4 + 3] = v.w;
  }
  __syncthreads();
#pragma unroll
  for (int i = 0; i < 4; ++i) {
    f16x4 o;
#pragma unroll
    for (int j = 0; j < 4; ++j) o[j] = (_Float16)T[tx * 4 + j][ty * 4 + i];
    *(f16x4*)(dst + (long)(r0 + ty * 4 + i) * CD + c0 + tx * 4) = o;
  }
}

// ============================================================================
// Diag-of-Gram reductions on f16 G.
// ============================================================================
__global__ __launch_bounds__(256) void row_sumsq(const _Float16* __restrict__ G, float* __restrict__ out, float inv)
{
  __shared__ float red[256];
  const int tid = threadIdx.x;
  const _Float16* row = G + (long)blockIdx.x * RD;
  float s = 0.f;
  for (int c = tid * 8; c < RD; c += 2048) {
    f16x8 v = *(const f16x8*)(row + c);
#pragma unroll
    for (int u = 0; u < 8; ++u) { float f = (float)v[u]; s += f * f; }
  }
  red[tid] = s; __syncthreads();
  for (int off = 128; off > 0; off >>= 1) { if (tid < off) red[tid] += red[tid + off]; __syncthreads(); }
  if (tid == 0) out[blockIdx.x] = red[0] * inv;
}

__global__ __launch_bounds__(256) void col_sumsq(const _Float16* __restrict__ G, float* __restrict__ out)
{
  const int rr = blockIdx.x * 256 + threadIdx.x;
  const int cc0 = blockIdx.y * 256;
  float s = 0.f;
  for (int i = 0; i < 256; ++i) {
    float v = (float)G[(long)(cc0 + i) * RD + rr];
    s += v * v;
  }
  atomicAdd(&out[rr], s * (1.f / (float)CD));
}

// ============================================================================
// 2-layer LSTM single step + linear head (unchanged from round 1).
// ============================================================================
__device__ __forceinline__ float sigm_(float x) { return 1.f / (1.f + __expf(-x)); }
__device__ __forceinline__ float tanh_(float x) { float e = __expf(2.f * x); return 1.f - 2.f / (e + 1.f); }

__global__ __launch_bounds__(256) void lstm_head(
    const float* __restrict__ diag, int B,
    const float* __restrict__ h0, const float* __restrict__ c0,
    const float* __restrict__ Wih0, const float* __restrict__ Whh0,
    const float* __restrict__ bih0, const float* __restrict__ bhh0,
    const float* __restrict__ Wih1, const float* __restrict__ Whh1,
    const float* __restrict__ bih1, const float* __restrict__ bhh1,
    const float* __restrict__ HW, const float* __restrict__ Hb,
    float* __restrict__ pre, float* __restrict__ sum_out)
{
  __shared__ float w0[80], wh0[1600], b0[80], wi1[1600], wh1[1600], b1[80], hw[20];
  __shared__ float red[256];
  const int tid = threadIdx.x;
  for (int i = tid; i < 80; i += 256) { w0[i] = Wih0[i]; b0[i] = bih0[i] + bhh0[i]; b1[i] = bih1[i] + bhh1[i]; }
  for (int i = tid; i < 1600; i += 256) { wh0[i] = Whh0[i]; wi1[i] = Wih1[i]; wh1[i] = Whh1[i]; }
  if (tid < 20) hw[tid] = HW[tid];
  __syncthreads();

  const int b = blockIdx.x * 256 + tid;
  const float d = diag[b];
  float x = logf(fabsf(d)) * 0.1f;
  x = fminf(fmaxf(x, -1.f), 1.f);

  const float* h0p = h0 + (long)b * 20;
  const float* c0p = c0 + (long)b * 20;
  const float* h1p = h0 + (long)B * 20 + (long)b * 20;
  const float* c1p = c0 + (long)B * 20 + (long)b * 20;

  float h0r[20], hA[20];
#pragma unroll
  for (int m = 0; m < 20; ++m) h0r[m] = h0p[m];
#pragma unroll
  for (int h = 0; h < 20; ++h) {
    float gi = w0[h] * x + b0[h];
    float gf = w0[20 + h] * x + b0[20 + h];
    float gg = w0[40 + h] * x + b0[40 + h];
    float go = w0[60 + h] * x + b0[60 + h];
#pragma unroll
    for (int m = 0; m < 20; ++m) {
      const float hm = h0r[m];
      gi += wh0[h * 20 + m] * hm;
      gf += wh0[(20 + h) * 20 + m] * hm;
      gg += wh0[(40 + h) * 20 + m] * hm;
      go += wh0[(60 + h) * 20 + m] * hm;
    }
    const float cc = sigm_(gf) * c0p[h] + sigm_(gi) * tanh_(gg);
    hA[h] = sigm_(go) * tanh_(cc);
  }
  float h1r[20];
#pragma unroll
  for (int m = 0; m < 20; ++m) h1r[m] = h1p[m];
  float pr = 0.f;
#pragma unroll
  for (int h = 0; h < 20; ++h) {
    float gi = b1[h], gf = b1[20 + h], gg = b1[40 + h], go = b1[60 + h];
#pragma unroll
    for (int m = 0; m < 20; ++m) {
      const float am = hA[m], hm = h1r[m];
      gi += wi1[h * 20 + m] * am + wh1[h * 20 + m] * hm;
      gf += wi1[(20 + h) * 20 + m] * am + wh1[(20 + h) * 20 + m] * hm;
      gg += wi1[(40 + h) * 20 + m] * am + wh1[(40 + h) * 20 + m] * hm;
      go += wi1[(60 + h) * 20 + m] * am + wh1[(60 + h) * 20 + m] * hm;
    }
    const float cc = sigm_(gf) * c1p[h] + sigm_(gi) * tanh_(gg);
    pr += sigm_(go) * tanh_(cc) * hw[h];
  }
  pr = (pr + Hb[0]) * 0.1f;
  pre[b] = pr;

  red[tid] = pr; __syncthreads();
  for (int off = 128; off > 0; off >>= 1) { if (tid < off) red[tid] += red[tid + off]; __syncthreads(); }
  if (tid == 0) atomicAdd(sum_out, red[0]);
}

// ============================================================================
// Pt[cc][rr] = Rv(cc) * Gt[cc][rr] * Lv(rr), in place on f16.
// ============================================================================
__global__ __launch_bounds__(256) void scale_P(
    _Float16* __restrict__ G, const float* __restrict__ lpre, const float* __restrict__ rpre,
    const float* __restrict__ Lbef, const float* __restrict__ Rbef, const float* __restrict__ sums)
{
  const long id4 = ((long)blockIdx.x * 256 + threadIdx.x) * 4;
  const int cc = (int)(id4 >> 13);
  const int rr = (int)(id4 & (RD - 1));
  const float meanl = sums[0] * (1.f / (float)RD);
  const float meanr = sums[1] * (1.f / (float)CD);
  const float rv = fmaxf(rpre[cc] - meanr + 1.f, Rbef[cc]);
  f16x4 g = *(f16x4*)(G + id4);
  float4 lp = *(const float4*)(lpre + rr);
  float4 lb = *(const float4*)(Lbef + rr);
  g[0] = (_Float16)((float)g[0] * rv * fmaxf(lp.x - meanl + 1.f, lb.x));
  g[1] = (_Float16)((float)g[1] * rv * fmaxf(lp.y - meanl + 1.f, lb.y));
  g[2] = (_Float16)((float)g[2] * rv * fmaxf(lp.z - meanl + 1.f, lb.z));
  g[3] = (_Float16)((float)g[3] * rv * fmaxf(lp.w - meanl + 1.f, lb.w));
  *(f16x4*)(G + id4) = g;
}

// ============================================================================
// Blocked Cholesky (NB=64) of S (2048x2048 fp32, lower); invD[kb] = inv(L_kk).
// ============================================================================
__global__ __launch_bounds__(256) void potrf64(float* __restrict__ S, float* __restrict__ invD, int kb)
{
  __shared__ float Ls[64][65];
  __shared__ float Ws[64][65];
  const int tid = threadIdx.x;
  const int tx = tid & 15, ty = tid >> 4;
  const long o = (long)kb * 64;

  for (int t = tid; t < 4096; t += 256) { int r = t >> 6, c = t & 63; Ls[r][c] = S[(o + r) * CD + o + c]; }
  __syncthreads();

  for (int j = 0; j < 64; ++j) {
    const float dj = Ls[j][j];
    const float sd = sqrtf(dj);
    const float rd = 1.f / sd;
    __syncthreads();
    for (int i = j + tid; i < 64; i += 256) Ls[i][j] *= rd;
    __syncthreads();
    for (int i = j + 1 + ty; i < 64; i += 16) {
      const float lij = Ls[i][j];
      for (int c = j + 1 + tx; c < 64; c += 16) Ls[i][c] -= lij * Ls[c][j];
    }
    __syncthreads();
  }

  if (tid < 64) {
    const int c = tid;
    for (int i = 0; i < c; ++i) Ws[i][c] = 0.f;
    Ws[c][c] = 1.f / Ls[c][c];
    for (int i = c + 1; i < 64; ++i) {
      float s = 0.f;
      for (int m = c; m < i; ++m) s += Ls[i][m] * Ws[m][c];
      Ws[i][c] = -s / Ls[i][i];
    }
  }
  __syncthreads();

  for (int t = tid; t < 4096; t += 256) {
    int r = t >> 6, c = t & 63;
    if (c <= r) S[(o + r) * CD + o + c] = Ls[r][c];
    invD[(long)kb * 4096 + t] = Ws[r][c];
  }
}

__global__ __launch_bounds__(256) void panel64(float* __restrict__ S, const float* __restrict__ invD, int kb)
{
  __shared__ float Ss[64][65];
  __shared__ float Ws[64][65];
  const int tid = threadIdx.x, tx = tid & 15, ty = tid >> 4;
  const int ib = kb + 1 + blockIdx.x;
  const long ro = (long)ib * 64, co = (long)kb * 64;
  for (int t = tid; t < 4096; t += 256) {
    int r = t >> 6, c = t & 63;
    Ss[r][c] = S[(ro + r) * CD + co + c];
    Ws[r][c] = invD[(long)kb * 4096 + t];
  }
  __syncthreads();
  float acc[4][4];
#pragma unroll
  for (int i = 0; i < 4; ++i)
#pragma unroll
    for (int j = 0; j < 4; ++j) acc[i][j] = 0.f;
#pragma unroll 4
  for (int m = 0; m < 64; ++m) {
    float a[4], w[4];
#pragma unroll
    for (int i = 0; i < 4; ++i) { a[i] = Ss[ty * 4 + i][m]; w[i] = Ws[tx * 4 + i][m]; }
#pragma unroll
    for (int i = 0; i < 4; ++i)
#pragma unroll
      for (int j = 0; j < 4; ++j) acc[i][j] += a[i] * w[j];
  }
#pragma unroll
  for (int i = 0; i < 4; ++i)
#pragma unroll
    for (int j = 0; j < 4; ++j)
      S[(ro + ty * 4 + i) * CD + co + tx * 4 + j] = acc[i][j];
}

__global__ __launch_bounds__(256) void trail64(float* __restrict__ S, int kb)
{
  const int jb = kb + 1 + blockIdx.x, ib = kb + 1 + blockIdx.y;
  if (jb > ib) return;
  __shared__ float Li[64][65];
  __shared__ float Lj[64][65];
  const int tid = threadIdx.x, tx = tid & 15, ty = tid >> 4;
  const long io = (long)ib * 64, jo = (long)jb * 64, ko = (long)kb * 64;
  for (int t = tid; t < 4096; t += 256) {
    int r = t >> 6, c = t & 63;
    Li[r][c] = S[(io + r) * CD + ko + c];
    Lj[r][c] = S[(jo + r) * CD + ko + c];
  }
  __syncthreads();
  float acc[4][4];
#pragma unroll
  for (int i = 0; i < 4; ++i)
#pragma unroll
    for (int j = 0; j < 4; ++j) acc[i][j] = 0.f;
#pragma unroll 4
  for (int m = 0; m < 64; ++m) {
    float a[4], w[4];
#pragma unroll
    for (int i = 0; i < 4; ++i) { a[i] = Li[ty * 4 + i][m]; w[i] = Lj[tx * 4 + i][m]; }
#pragma unroll
    for (int i = 0; i < 4; ++i)
#pragma unroll
      for (int j = 0; j < 4; ++j) acc[i][j] += a[i] * w[j];
  }
#pragma unroll
  for (int i = 0; i < 4; ++i)
#pragma unroll
    for (int j = 0; j < 4; ++j) {
      const long off = (io + ty * 4 + i) * CD + jo + tx * 4 + j;
      S[off] -= acc[i][j];
    }
}

// ============================================================================
// Blocked forward solve: L * Qt = Xt (Xt in f16), Qt = d_out (fp32).
// ============================================================================
__global__ __launch_bounds__(256) void solve64(
    const float* __restrict__ S, const float* __restrict__ invD,
    const _Float16* __restrict__ X, float* __restrict__ Q, int ib)
{
  __shared__ float Lb[64][65];
  __shared__ float Qb[64][68];
  const int tid = threadIdx.x, tx = tid & 15, ty = tid >> 4;
  const int c0 = blockIdx.x * 64;
  const long r0 = (long)ib * 64;

  float acc[4][4];
#pragma unroll
  for (int i = 0; i < 4; ++i) {
    f16x4 v = *(const f16x4*)(X + (r0 + ty * 4 + i) * RD + c0 + tx * 4);
    acc[i][0] = (float)v[0]; acc[i][1] = (float)v[1]; acc[i][2] = (float)v[2]; acc[i][3] = (float)v[3];
  }
  for (int jb = 0; jb < ib; ++jb) {
    __syncthreads();
    for (int t = tid; t < 4096; t += 256) {
      int r = t >> 6, c = t & 63;
      Lb[r][c] = S[(r0 + r) * CD + (long)jb * 64 + c];
      Qb[r][c] = Q[((long)jb * 64 + r) * RD + c0 + c];
    }
    __syncthreads();
#pragma unroll 4
    for (int m = 0; m < 64; ++m) {
      float l[4], q[4];
#pragma unroll
      for (int i = 0; i < 4; ++i) { l[i] = Lb[ty * 4 + i][m]; q[i] = Qb[m][tx * 4 + i]; }
#pragma unroll
      for (int i = 0; i < 4; ++i)
#pragma unroll
        for (int j = 0; j < 4; ++j) acc[i][j] -= l[i] * q[j];
    }
  }
  __syncthreads();
#pragma unroll
  for (int i = 0; i < 4; ++i) {
    float4 v; v.x = acc[i][0]; v.y = acc[i][1]; v.z = acc[i][2]; v.w = acc[i][3];
    *(float4*)&Qb[ty * 4 + i][tx * 4] = v;
  }
  for (int t = tid; t < 4096; t += 256) Lb[t >> 6][t & 63] = invD[(long)ib * 4096 + t];
  __syncthreads();

  float o_[4][4];
#pragma unroll
  for (int i = 0; i < 4; ++i)
#pragma unroll
    for (int j = 0; j < 4; ++j) o_[i][j] = 0.f;
#pragma unroll 4
  for (int m = 0; m < 64; ++m) {
    float l[4], q[4];
#pragma unroll
    for (int i = 0; i < 4; ++i) { l[i] = Lb[ty * 4 + i][m]; q[i] = Qb[m][tx * 4 + i]; }
#pragma unroll
    for (int i = 0; i < 4; ++i)
#pragma unroll
      for (int j = 0; j < 4; ++j) o_[i][j] += l[i] * q[j];
  }
#pragma unroll
  for (int i = 0; i < 4; ++i) {
    float4 v; v.x = o_[i][0]; v.y = o_[i][1]; v.z = o_[i][2]; v.w = o_[i][3];
    *(float4*)(Q + (r0 + ty * 4 + i) * RD + c0 + tx * 4) = v;
  }
}

// ============================================================================
// Host launch.
// ws (80.1 MB): vec 128K | SYM fp32 16M | OVL 32M (Cp z0/z1 -> SYM_f16 -> invD)
//               | BIG f16 32M (Gt -> Pt -> Xt in place)
// d_out (64 MB): [0:32M) Mt_f16, [32M:64M) Sgt_f16 -> Mtr_f16; then Q (fp32).
// ============================================================================
extern "C" void kernel_launch(void* const* d_in, const int* in_sizes, int n_in,
                              void* d_out, int out_size, void* d_ws, size_t ws_size,
                              hipStream_t stream)
{
  const float* s_in  = (const float*)d_in[0];
  const float* sgrad = (const float*)d_in[1];
  const float* L_h0  = (const float*)d_in[2];
  const float* L_c0  = (const float*)d_in[3];
  const float* R_h0  = (const float*)d_in[4];
  const float* R_c0  = (const float*)d_in[5];
  const float* L_bef = (const float*)d_in[6];
  const float* R_bef = (const float*)d_in[7];
  const float* Wih0  = (const float*)d_in[8];
  const float* Whh0  = (const float*)d_in[9];
  const float* bih0  = (const float*)d_in[10];
  const float* bhh0  = (const float*)d_in[11];
  const float* Wih1  = (const float*)d_in[12];
  const float* Whh1  = (const float*)d_in[13];
  const float* bih1  = (const float*)d_in[14];
  const float* bhh1  = (const float*)d_in[15];
  const float* L_W   = (const float*)d_in[16];
  const float* L_b   = (const float*)d_in[17];
  const float* R_W   = (const float*)d_in[18];
  const float* R_b   = (const float*)d_in[19];

  float* out = (float*)d_out;
  char*  ws  = (char*)d_ws;

  const size_t SYM_OFF = (size_t)1 << 17;
  const size_t OVL_OFF = SYM_OFF + ((size_t)16 << 20);
  const size_t BIG_OFF = OVL_OFF + ((size_t)32 << 20);
  float* vec  = (float*)ws;
  float* sums = vec;
  float* ggt  = vec + 4;
  float* gtg  = ggt + RD;
  float* lpre = gtg + CD;
  float* rpre = lpre + RD;
  float*     SYM   = (float*)(ws + SYM_OFF);
  float*     Cp    = (float*)(ws + OVL_OFF);       // 2 x 16 MB split-K partials
  _Float16*  SYMh  = (_Float16*)(ws + OVL_OFF);    // overlaid (disjoint lifetime)
  float*     invD  = (float*)(ws + OVL_OFF);       // overlaid (disjoint lifetime)
  _Float16*  BIG   = (_Float16*)(ws + BIG_OFF);    // Gt -> Pt -> Xt (f16)

  _Float16* Mt_h  = (_Float16*)d_out;              // [0 : 32MB)
  _Float16* slotB = Mt_h + (long)CD * RD;          // Sgt_f16 -> Mtr_f16

  hipMemsetAsync(vec, 0, (4 + RD) * sizeof(float), stream);

  const dim3 blk(256);
  const dim3 gK8(16, 16, 2);    // M=N=2048, K=8192, split-K 2
  const dim3 gK2(64, 16, 1);    // M=2048, N=8192, K=2048
  const dim3 gSym(32, 32);
  const int  castBlocks = (CD * RD / 4) / 256;

  // --- f16 copies of M and 0.1-graded s_grad's raw values ---
  cast_f16<<<castBlocks, blk, 0, stream>>>(s_in, Mt_h);
  cast_f16<<<castBlocks, blk, 0, stream>>>(sgrad, slotB);

  // --- Asym = 0.05 * sym(Mt * Sgt^T) ---
  gemm_nt_f16<<<gK8, blk, 0, stream>>>(Mt_h, slotB, Cp, nullptr, nullptr, nullptr,
                                       CD, CD, RD, 2, 0.f, 0.f, 1.f);
  sym_combine<<<gSym, blk, 0, stream>>>(Cp, SYM, CD, 2, 0.05f);
  cast_f16<<<(CD * CD / 4) / 256, blk, 0, stream>>>(SYM, SYMh);

  // --- Mtr (M transposed, f16) replaces Sgt in slotB ---
  transpose_cast_f16<<<dim3(RD / 64, CD / 64), blk, 0, stream>>>(s_in, slotB);

  // --- Gt = 0.1*Sgt - Asym*Mt  (f16 out into BIG) ---
  gemm_nt_f16<<<gK2, blk, 0, stream>>>(SYMh, slotB, nullptr, BIG, sgrad, nullptr,
                                       CD, RD, CD, 1, 0.1f, 0.f, -1.f);

  // --- diag Gram reductions ---
  row_sumsq<<<CD, blk, 0, stream>>>(BIG, gtg, 1.f / (float)RD);
  col_sumsq<<<dim3(RD / 256, CD / 256), blk, 0, stream>>>(BIG, ggt);

  // --- LSTM heads ---
  lstm_head<<<RD / 256, blk, 0, stream>>>(ggt, RD, L_h0, L_c0, Wih0, Whh0, bih0, bhh0,
                                          Wih1, Whh1, bih1, bhh1, L_W, L_b, lpre, &sums[0]);
  lstm_head<<<CD / 256, blk, 0, stream>>>(gtg, CD, R_h0, R_c0, Wih0, Whh0, bih0, bhh0,
                                          Wih1, Whh1, bih1, bhh1, R_W, R_b, rpre, &sums[1]);

  // --- P = Lv * G * Rv (in place, f16) ---
  scale_P<<<(CD * (RD / 4)) / 256, blk, 0, stream>>>(BIG, lpre, rpre, L_bef, R_bef, sums);

  // --- Bsym = 0.5 * sym(Mt * Pt^T) ---
  gemm_nt_f16<<<gK8, blk, 0, stream>>>(Mt_h, BIG, Cp, nullptr, nullptr, nullptr,
                                       CD, CD, RD, 2, 0.f, 0.f, 1.f);
  sym_combine<<<gSym, blk, 0, stream>>>(Cp, SYM, CD, 2, 0.5f);
  cast_f16<<<(CD * CD / 4) / 256, blk, 0, stream>>>(SYM, SYMh);

  // --- Xt = Mt - Pt + Bsym*Mt (in place: E = Pt read once per element) ---
  gemm_nt_f16<<<gK2, blk, 0, stream>>>(SYMh, slotB, nullptr, BIG, s_in, BIG,
                                       CD, RD, CD, 1, 1.f, -1.f, 1.f);

  // --- Gram S = 0.5 * sym(Xt * Xt^T) ---
  gemm_nt_f16<<<gK8, blk, 0, stream>>>(BIG, BIG, Cp, nullptr, nullptr, nullptr,
                                       CD, CD, RD, 2, 0.f, 0.f, 1.f);
  sym_combine<<<gSym, blk, 0, stream>>>(Cp, SYM, CD, 2, 0.5f);

  // --- Cholesky ladder + forward solve ---
  for (int kb = 0; kb < 32; ++kb) {
    potrf64<<<1, blk, 0, stream>>>(SYM, invD, kb);
    const int nrem = 31 - kb;
    if (nrem > 0) {
      panel64<<<nrem, blk, 0, stream>>>(SYM, invD, kb);
      trail64<<<dim3(nrem, nrem), blk, 0, stream>>>(SYM, kb);
    }
  }
  for (int ib = 0; ib < 32; ++ib)
    solve64<<<RD / 64, blk, 0, stream>>>(SYM, invD, BIG, out, ib);
}

// Round 3
// 4663.610 us; speedup vs baseline: 2.1486x; 1.3204x over previous
//
#include <hip/hip_runtime.h>
#include <math.h>

#define RD 8192   // r (long dim, contiguous in storage)
#define CD 2048   // c (short dim, rows in storage)

typedef _Float16 f16x8 __attribute__((ext_vector_type(8)));
typedef _Float16 f16x4 __attribute__((ext_vector_type(4)));
typedef float    f32x4 __attribute__((ext_vector_type(4)));

#define GLOBAL_AS __attribute__((address_space(1)))
#define LDS_AS    __attribute__((address_space(3)))

// ============================================================================
// f16 MFMA GEMM (NT): C[i][j] = sum_k A[i*K+k] * B[j*K+k], fp32 accumulate.
// mode A (Cp != 0): fp32 partials Cp[z][i][j] (split-K via blockIdx.z)
// mode B (Cp == 0): Of16[i][j] = f16( sgn*acc + beta*Dg[ij] + gamma*Eg[ij] )
// ============================================================================
__global__ __launch_bounds__(256) void gemm_nt_f16(
    const _Float16* __restrict__ A, const _Float16* __restrict__ B,
    float* __restrict__ Cp, _Float16* __restrict__ Of16,
    const float* __restrict__ Dg, const _Float16* __restrict__ Eg,
    int M, int N, int K, int ksplit, float beta, float gamma, float sgn)
{
  __shared__ __align__(1024) _Float16 As[128 * 32];
  __shared__ __align__(1024) _Float16 Bs[128 * 32];
  const int tid = threadIdx.x;
  const int wave = tid >> 6, lane = tid & 63;
  const int wy = wave >> 1, wx = wave & 1;
  const int bi = blockIdx.y * 128, bj = blockIdx.x * 128;
  const int kchunk = K / ksplit;
  const long k0 = (long)blockIdx.z * kchunk;

  f32x4 acc[4][4];
#pragma unroll
  for (int i = 0; i < 4; ++i)
#pragma unroll
    for (int j = 0; j < 4; ++j) acc[i][j] = (f32x4){0.f, 0.f, 0.f, 0.f};

  const int srow = wave * 16 + (lane >> 2);
  const int skof = (lane & 3) * 8;
  const _Float16* aA = A + (long)(bi + srow) * K + k0 + skof;
  const _Float16* aB = B + (long)(bj + srow) * K + k0 + skof;
  _Float16* lA = As + wave * 16 * 32;
  _Float16* lB = Bs + wave * 16 * 32;

  const int fr = lane & 15;
  const int fk = (lane >> 4) * 8;

  for (int kt = 0; kt < kchunk; kt += 32) {
    __syncthreads();
#pragma unroll
    for (int q = 0; q < 2; ++q) {
      __builtin_amdgcn_global_load_lds(
          (const GLOBAL_AS unsigned int*)(aA + (long)q * 64 * K + kt),
          (LDS_AS unsigned int*)(lA + q * 64 * 32), 16, 0, 0);
      __builtin_amdgcn_global_load_lds(
          (const GLOBAL_AS unsigned int*)(aB + (long)q * 64 * K + kt),
          (LDS_AS unsigned int*)(lB + q * 64 * 32), 16, 0, 0);
    }
    __syncthreads();

    f16x8 af[4], bf[4];
#pragma unroll
    for (int t = 0; t < 4; ++t) {
      af[t] = *(const f16x8*)(As + (wy * 64 + t * 16 + fr) * 32 + fk);
      bf[t] = *(const f16x8*)(Bs + (wx * 64 + t * 16 + fr) * 32 + fk);
    }
#pragma unroll
    for (int mt = 0; mt < 4; ++mt)
#pragma unroll
      for (int nt = 0; nt < 4; ++nt)
        acc[mt][nt] = __builtin_amdgcn_mfma_f32_16x16x32_f16(af[mt], bf[nt], acc[mt][nt], 0, 0, 0);
  }

  const int quad = lane >> 4, fc = lane & 15;
  if (Cp) {
    float* Cz = Cp + (long)blockIdx.z * M * N;
#pragma unroll
    for (int mt = 0; mt < 4; ++mt)
#pragma unroll
      for (int nt = 0; nt < 4; ++nt) {
        const int col = bj + wx * 64 + nt * 16 + fc;
#pragma unroll
        for (int reg = 0; reg < 4; ++reg) {
          const int row = bi + wy * 64 + mt * 16 + quad * 4 + reg;
          Cz[(long)row * N + col] = acc[mt][nt][reg];
        }
      }
  } else {
#pragma unroll
    for (int mt = 0; mt < 4; ++mt)
#pragma unroll
      for (int nt = 0; nt < 4; ++nt) {
        const int col = bj + wx * 64 + nt * 16 + fc;
#pragma unroll
        for (int reg = 0; reg < 4; ++reg) {
          const int row = bi + wy * 64 + mt * 16 + quad * 4 + reg;
          const long off = (long)row * N + col;
          float v = sgn * acc[mt][nt][reg];
          if (Dg) v += beta * Dg[off];
          if (Eg) v += gamma * (float)Eg[off];
          Of16[off] = (_Float16)v;
        }
      }
  }
}

// ============================================================================
// sym_combine: out[i][j] = scale * sum_z (Cp[z][i][j] + Cp[z][j][i]), n x n fp32.
// ============================================================================
__global__ __launch_bounds__(256) void sym_combine(
    const float* __restrict__ Cp, float* __restrict__ out, int n, int nsplit, float scale)
{
  __shared__ float Ts[64][68];
  const int tid = threadIdx.x;
  const int tx = tid & 15, ty = tid >> 4;
  const int bi = blockIdx.y * 64, bj = blockIdx.x * 64;
  float acc[4][4];
#pragma unroll
  for (int i = 0; i < 4; ++i)
#pragma unroll
    for (int j = 0; j < 4; ++j) acc[i][j] = 0.f;

  for (int s = 0; s < nsplit; ++s) {
    const float* C = Cp + (long)s * n * n;
#pragma unroll
    for (int i = 0; i < 4; ++i) {
      float4 v = *(const float4*)(C + (long)(bi + ty * 4 + i) * n + bj + tx * 4);
      acc[i][0] += v.x; acc[i][1] += v.y; acc[i][2] += v.z; acc[i][3] += v.w;
    }
    __syncthreads();
#pragma unroll
    for (int i = 0; i < 4; ++i) {
      float4 w = *(const float4*)(C + (long)(bj + ty * 4 + i) * n + bi + tx * 4);
      *(float4*)&Ts[ty * 4 + i][tx * 4] = w;
    }
    __syncthreads();
#pragma unroll
    for (int i = 0; i < 4; ++i)
#pragma unroll
      for (int j = 0; j < 4; ++j) acc[i][j] += Ts[tx * 4 + j][ty * 4 + i];
  }
#pragma unroll
  for (int i = 0; i < 4; ++i) {
    float4 v; v.x = scale * acc[i][0]; v.y = scale * acc[i][1]; v.z = scale * acc[i][2]; v.w = scale * acc[i][3];
    *(float4*)(out + (long)(bi + ty * 4 + i) * n + bj + tx * 4) = v;
  }
}

// ============================================================================
// Casts / transposes.
// ============================================================================
__global__ __launch_bounds__(256) void cast_f16(const float* __restrict__ s, _Float16* __restrict__ d)
{
  const long i = ((long)blockIdx.x * 256 + threadIdx.x) * 4;
  float4 v = *(const float4*)(s + i);
  f16x4 o; o[0] = (_Float16)v.x; o[1] = (_Float16)v.y; o[2] = (_Float16)v.z; o[3] = (_Float16)v.w;
  *(f16x4*)(d + i) = o;
}

__global__ __launch_bounds__(256) void cast_f32(const _Float16* __restrict__ s, float* __restrict__ d)
{
  const long i = ((long)blockIdx.x * 256 + threadIdx.x) * 8;
  f16x8 v = *(const f16x8*)(s + i);
  float4 a, b;
  a.x = (float)v[0]; a.y = (float)v[1]; a.z = (float)v[2]; a.w = (float)v[3];
  b.x = (float)v[4]; b.y = (float)v[5]; b.z = (float)v[6]; b.w = (float)v[7];
  *(float4*)(d + i) = a;
  *(float4*)(d + i + 4) = b;
}

__global__ __launch_bounds__(256) void transpose_cast_f16(
    const float* __restrict__ src, _Float16* __restrict__ dst)
{
  __shared__ float T[64][65];
  const int tid = threadIdx.x, tx = tid & 15, ty = tid >> 4;
  const int r0 = blockIdx.x * 64, c0 = blockIdx.y * 64;
#pragma unroll
  for (int i = 0; i < 4; ++i) {
    float4 v = *(const float4*)(src + (long)(c0 + ty * 4 + i) * RD + r0 + tx * 4);
    T[ty * 4 + i][tx * 4 + 0] = v.x; T[ty * 4 + i][tx * 4 + 1] = v.y;
    T[ty * 4 + i][tx * 4 + 2] = v.z; T[ty * 4 + i][tx * 4 + 3] = v.w;
  }
  __syncthreads();
#pragma unroll
  for (int i = 0; i < 4; ++i) {
    f16x4 o;
#pragma unroll
    for (int j = 0; j < 4; ++j) o[j] = (_Float16)T[tx * 4 + j][ty * 4 + i];
    *(f16x4*)(dst + (long)(r0 + ty * 4 + i) * CD + c0 + tx * 4) = o;
  }
}

// f16 (CD x RD) -> f16 (RD x CD) transpose, 64x64 tiles
__global__ __launch_bounds__(256) void transpose_f16(
    const _Float16* __restrict__ src, _Float16* __restrict__ dst)
{
  __shared__ _Float16 T[64][72];
  const int tid = threadIdx.x;
  const int r0 = blockIdx.y * 64;   // src row (CD)
  const int c0 = blockIdx.x * 64;   // src col (RD)
  const int sr = tid >> 2, sc = (tid & 3) * 16;
  {
    f16x8 a = *(const f16x8*)(src + (long)(r0 + sr) * RD + c0 + sc);
    f16x8 b = *(const f16x8*)(src + (long)(r0 + sr) * RD + c0 + sc + 8);
    *(f16x8*)&T[sr][sc] = a;
    *(f16x8*)&T[sr][sc + 8] = b;
  }
  __syncthreads();
  {
    f16x8 a, b;
#pragma unroll
    for (int q = 0; q < 8; ++q) { a[q] = T[sc + q][sr]; b[q] = T[sc + 8 + q][sr]; }
    *(f16x8*)(dst + (long)(c0 + sr) * CD + r0 + sc) = a;
    *(f16x8*)(dst + (long)(c0 + sr) * CD + r0 + sc + 8) = b;
  }
}

// ============================================================================
// Diag-of-Gram reductions on f16 G.
// ============================================================================
__global__ __launch_bounds__(256) void row_sumsq(const _Float16* __restrict__ G, float* __restrict__ out, float inv)
{
  __shared__ float red[256];
  const int tid = threadIdx.x;
  const _Float16* row = G + (long)blockIdx.x * RD;
  float s = 0.f;
  for (int c = tid * 8; c < RD; c += 2048) {
    f16x8 v = *(const f16x8*)(row + c);
#pragma unroll
    for (int u = 0; u < 8; ++u) { float f = (float)v[u]; s += f * f; }
  }
  red[tid] = s; __syncthreads();
  for (int off = 128; off > 0; off >>= 1) { if (tid < off) red[tid] += red[tid + off]; __syncthreads(); }
  if (tid == 0) out[blockIdx.x] = red[0] * inv;
}

__global__ __launch_bounds__(256) void col_sumsq(const _Float16* __restrict__ G, float* __restrict__ out)
{
  const int rr = blockIdx.x * 256 + threadIdx.x;
  const int cc0 = blockIdx.y * 256;
  float s = 0.f;
  for (int i = 0; i < 256; ++i) {
    float v = (float)G[(long)(cc0 + i) * RD + rr];
    s += v * v;
  }
  atomicAdd(&out[rr], s * (1.f / (float)CD));
}

// ============================================================================
// 2-layer LSTM single step + linear head.
// ============================================================================
__device__ __forceinline__ float sigm_(float x) { return 1.f / (1.f + __expf(-x)); }
__device__ __forceinline__ float tanh_(float x) { float e = __expf(2.f * x); return 1.f - 2.f / (e + 1.f); }

__global__ __launch_bounds__(256) void lstm_head(
    const float* __restrict__ diag, int B,
    const float* __restrict__ h0, const float* __restrict__ c0,
    const float* __restrict__ Wih0, const float* __restrict__ Whh0,
    const float* __restrict__ bih0, const float* __restrict__ bhh0,
    const float* __restrict__ Wih1, const float* __restrict__ Whh1,
    const float* __restrict__ bih1, const float* __restrict__ bhh1,
    const float* __restrict__ HW, const float* __restrict__ Hb,
    float* __restrict__ pre, float* __restrict__ sum_out)
{
  __shared__ float w0[80], wh0[1600], b0[80], wi1[1600], wh1[1600], b1[80], hw[20];
  __shared__ float red[256];
  const int tid = threadIdx.x;
  for (int i = tid; i < 80; i += 256) { w0[i] = Wih0[i]; b0[i] = bih0[i] + bhh0[i]; b1[i] = bih1[i] + bhh1[i]; }
  for (int i = tid; i < 1600; i += 256) { wh0[i] = Whh0[i]; wi1[i] = Wih1[i]; wh1[i] = Whh1[i]; }
  if (tid < 20) hw[tid] = HW[tid];
  __syncthreads();

  const int b = blockIdx.x * 256 + tid;
  const float d = diag[b];
  float x = logf(fabsf(d)) * 0.1f;
  x = fminf(fmaxf(x, -1.f), 1.f);

  const float* h0p = h0 + (long)b * 20;
  const float* c0p = c0 + (long)b * 20;
  const float* h1p = h0 + (long)B * 20 + (long)b * 20;
  const float* c1p = c0 + (long)B * 20 + (long)b * 20;

  float h0r[20], hA[20];
#pragma unroll
  for (int m = 0; m < 20; ++m) h0r[m] = h0p[m];
#pragma unroll
  for (int h = 0; h < 20; ++h) {
    float gi = w0[h] * x + b0[h];
    float gf = w0[20 + h] * x + b0[20 + h];
    float gg = w0[40 + h] * x + b0[40 + h];
    float go = w0[60 + h] * x + b0[60 + h];
#pragma unroll
    for (int m = 0; m < 20; ++m) {
      const float hm = h0r[m];
      gi += wh0[h * 20 + m] * hm;
      gf += wh0[(20 + h) * 20 + m] * hm;
      gg += wh0[(40 + h) * 20 + m] * hm;
      go += wh0[(60 + h) * 20 + m] * hm;
    }
    const float cc = sigm_(gf) * c0p[h] + sigm_(gi) * tanh_(gg);
    hA[h] = sigm_(go) * tanh_(cc);
  }
  float h1r[20];
#pragma unroll
  for (int m = 0; m < 20; ++m) h1r[m] = h1p[m];
  float pr = 0.f;
#pragma unroll
  for (int h = 0; h < 20; ++h) {
    float gi = b1[h], gf = b1[20 + h], gg = b1[40 + h], go = b1[60 + h];
#pragma unroll
    for (int m = 0; m < 20; ++m) {
      const float am = hA[m], hm = h1r[m];
      gi += wi1[h * 20 + m] * am + wh1[h * 20 + m] * hm;
      gf += wi1[(20 + h) * 20 + m] * am + wh1[(20 + h) * 20 + m] * hm;
      gg += wi1[(40 + h) * 20 + m] * am + wh1[(40 + h) * 20 + m] * hm;
      go += wi1[(60 + h) * 20 + m] * am + wh1[(60 + h) * 20 + m] * hm;
    }
    const float cc = sigm_(gf) * c1p[h] + sigm_(gi) * tanh_(gg);
    pr += sigm_(go) * tanh_(cc) * hw[h];
  }
  pr = (pr + Hb[0]) * 0.1f;
  pre[b] = pr;

  red[tid] = pr; __syncthreads();
  for (int off = 128; off > 0; off >>= 1) { if (tid < off) red[tid] += red[tid + off]; __syncthreads(); }
  if (tid == 0) atomicAdd(sum_out, red[0]);
}

// ============================================================================
// Pt[cc][rr] = Rv(cc) * Gt[cc][rr] * Lv(rr), in place on f16.
// ============================================================================
__global__ __launch_bounds__(256) void scale_P(
    _Float16* __restrict__ G, const float* __restrict__ lpre, const float* __restrict__ rpre,
    const float* __restrict__ Lbef, const float* __restrict__ Rbef, const float* __restrict__ sums)
{
  const long id4 = ((long)blockIdx.x * 256 + threadIdx.x) * 4;
  const int cc = (int)(id4 >> 13);
  const int rr = (int)(id4 & (RD - 1));
  const float meanl = sums[0] * (1.f / (float)RD);
  const float meanr = sums[1] * (1.f / (float)CD);
  const float rv = fmaxf(rpre[cc] - meanr + 1.f, Rbef[cc]);
  f16x4 g = *(f16x4*)(G + id4);
  float4 lp = *(const float4*)(lpre + rr);
  float4 lb = *(const float4*)(Lbef + rr);
  g[0] = (_Float16)((float)g[0] * rv * fmaxf(lp.x - meanl + 1.f, lb.x));
  g[1] = (_Float16)((float)g[1] * rv * fmaxf(lp.y - meanl + 1.f, lb.y));
  g[2] = (_Float16)((float)g[2] * rv * fmaxf(lp.z - meanl + 1.f, lb.z));
  g[3] = (_Float16)((float)g[3] * rv * fmaxf(lp.w - meanl + 1.f, lb.w));
  *(f16x4*)(G + id4) = g;
}

// ============================================================================
// potrf64v2: factor 64x64 diag block of S (fp32) -> L (lower, in place).
// Also: W diag block <- inv(Lkk) (zeros upper), Kinv <- inv(Lkk)^T inv(Lkk).
// ============================================================================
__global__ __launch_bounds__(256) void potrf64v2(
    float* __restrict__ S, float* __restrict__ W, float* __restrict__ Kinv, int kb)
{
  __shared__ float Ls[64][65];
  __shared__ float Ws[64][65];
  const int tid = threadIdx.x;
  const int tx = tid & 15, ty = tid >> 4;
  const long o = (long)kb * 64;

  for (int t = tid; t < 4096; t += 256) { int r = t >> 6, c = t & 63; Ls[r][c] = S[(o + r) * CD + o + c]; }
  __syncthreads();

  for (int j = 0; j < 64; ++j) {
    const float dj = Ls[j][j];
    const float sd = sqrtf(dj);
    const float rd = 1.f / sd;
    __syncthreads();
    for (int i = j + tid; i < 64; i += 256) Ls[i][j] *= rd;
    __syncthreads();
    for (int i = j + 1 + ty; i < 64; i += 16) {
      const float lij = Ls[i][j];
      for (int c = j + 1 + tx; c < 64; c += 16) Ls[i][c] -= lij * Ls[c][j];
    }
    __syncthreads();
  }

  if (tid < 64) {           // inv(L) forward substitution, one lane per column
    const int c = tid;
    for (int i = 0; i < c; ++i) Ws[i][c] = 0.f;
    Ws[c][c] = 1.f / Ls[c][c];
    for (int i = c + 1; i < 64; ++i) {
      float s = 0.f;
      for (int m = c; m < i; ++m) s += Ls[i][m] * Ws[m][c];
      Ws[i][c] = -s / Ls[i][i];
    }
  }
  __syncthreads();

  for (int t = tid; t < 4096; t += 256) {
    int r = t >> 6, c = t & 63;
    if (c <= r) S[(o + r) * CD + o + c] = Ls[r][c];
    W[(o + r) * 2048 + o + c] = Ws[r][c];
  }
  // Kinv = Ws^T * Ws
  float acc[4][4];
#pragma unroll
  for (int i = 0; i < 4; ++i)
#pragma unroll
    for (int j = 0; j < 4; ++j) acc[i][j] = 0.f;
  for (int m = 0; m < 64; ++m) {
    float a[4], b2[4];
#pragma unroll
    for (int q = 0; q < 4; ++q) { a[q] = Ws[m][ty * 4 + q]; b2[q] = Ws[m][tx * 4 + q]; }
#pragma unroll
    for (int i = 0; i < 4; ++i)
#pragma unroll
      for (int j = 0; j < 4; ++j) acc[i][j] += a[i] * b2[j];
  }
#pragma unroll
  for (int i = 0; i < 4; ++i)
#pragma unroll
    for (int j = 0; j < 4; ++j)
      Kinv[(ty * 4 + i) * 64 + tx * 4 + j] = acc[i][j];
}

// ============================================================================
// ptstep: fused panel + trailing update for step kb.
// by==0 (panel): L(ib,kb) = Spre(ib,kb)*Ws^T, stored TRANSPOSED in the upper
//   mirror S[kb-block rows, ib-block cols]. Reads only pre-step values.
// by>=1 (trail): S(ib,jb) -= Spre(ib,kb)*Kinv*Spre(jb,kb)^T  (pre-step reads
//   only -> no dependency on panel within the same dispatch).
// ============================================================================
__global__ __launch_bounds__(256) void ptstep(
    float* __restrict__ S, const float* __restrict__ W, const float* __restrict__ Kinv, int kb)
{
  __shared__ float As[64][68];
  __shared__ float Bs[64][68];
  __shared__ float Ts[64][68];
  const int tid = threadIdx.x, tx = tid & 15, ty = tid >> 4;
  const long ko = (long)kb * 64;

  if (blockIdx.y == 0) {
    const int ib = kb + 1 + blockIdx.x;
    const long ro = (long)ib * 64;
    for (int t = tid; t < 4096; t += 256) {
      int r = t >> 6, c = t & 63;
      As[r][c] = S[(ro + r) * CD + ko + c];
      Bs[r][c] = W[(ko + r) * 2048 + ko + c];   // Ws = inv(Lkk)
    }
    __syncthreads();
    float acc[4][4];
#pragma unroll
    for (int i = 0; i < 4; ++i)
#pragma unroll
      for (int j = 0; j < 4; ++j) acc[i][j] = 0.f;
    for (int m = 0; m < 64; ++m) {
      float a[4], w[4];
#pragma unroll
      for (int q = 0; q < 4; ++q) { a[q] = As[ty * 4 + q][m]; w[q] = Bs[tx * 4 + q][m]; }
#pragma unroll
      for (int i = 0; i < 4; ++i)
#pragma unroll
        for (int j = 0; j < 4; ++j) acc[i][j] += a[i] * w[j];
    }
    // store transposed: S[kb-row j][ib-col i] = Lblk[i][j]
#pragma unroll
    for (int i = 0; i < 4; ++i)
#pragma unroll
      for (int j = 0; j < 4; ++j)
        S[(ko + tx * 4 + j) * CD + ro + ty * 4 + i] = acc[i][j];
  } else {
    const int ib = kb + blockIdx.y;            // 1..nrem -> kb+1..31
    const int jb = kb + 1 + blockIdx.x;
    if (jb > ib) return;
    const long io = (long)ib * 64, jo = (long)jb * 64;
    for (int t = tid; t < 4096; t += 256) {
      int r = t >> 6, c = t & 63;
      As[r][c] = S[(io + r) * CD + ko + c];
      Bs[r][c] = Kinv[t];
    }
    __syncthreads();
    float acc[4][4];
#pragma unroll
    for (int i = 0; i < 4; ++i)
#pragma unroll
      for (int j = 0; j < 4; ++j) acc[i][j] = 0.f;
    for (int m = 0; m < 64; ++m) {
      float a[4], k2[4];
#pragma unroll
      for (int q = 0; q < 4; ++q) { a[q] = As[ty * 4 + q][m]; k2[q] = Bs[m][tx * 4 + q]; }
#pragma unroll
      for (int i = 0; i < 4; ++i)
#pragma unroll
        for (int j = 0; j < 4; ++j) acc[i][j] += a[i] * k2[j];
    }
#pragma unroll
    for (int i = 0; i < 4; ++i)
#pragma unroll
      for (int j = 0; j < 4; ++j) Ts[ty * 4 + i][tx * 4 + j] = acc[i][j];
    __syncthreads();
    for (int t = tid; t < 4096; t += 256) {
      int r = t >> 6, c = t & 63;
      Bs[r][c] = S[(jo + r) * CD + ko + c];
    }
    __syncthreads();
    float acc2[4][4];
#pragma unroll
    for (int i = 0; i < 4; ++i)
#pragma unroll
      for (int j = 0; j < 4; ++j) acc2[i][j] = 0.f;
    for (int m = 0; m < 64; ++m) {
      float t2[4], b2[4];
#pragma unroll
      for (int q = 0; q < 4; ++q) { t2[q] = Ts[ty * 4 + q][m]; b2[q] = Bs[tx * 4 + q][m]; }
#pragma unroll
      for (int i = 0; i < 4; ++i)
#pragma unroll
        for (int j = 0; j < 4; ++j) acc2[i][j] += t2[i] * b2[j];
    }
#pragma unroll
    for (int i = 0; i < 4; ++i)
#pragma unroll
      for (int j = 0; j < 4; ++j)
        S[(io + ty * 4 + i) * CD + jo + tx * 4 + j] -= acc2[i][j];
  }
}

// ============================================================================
// W = inv(L) by block doubling. Level s: for each pair p (b = 2ps):
//   W[b+s.., b..] = -Wc * Bm * Wa,  Bm stored transposed in S's upper mirror.
// winv_tn: T[p] = Bmt^T * Wa ; winv_nn: W21 = -Wc * T[p].
// ============================================================================
__global__ __launch_bounds__(256) void winv_tn(
    const float* __restrict__ S, const float* __restrict__ W, float* __restrict__ T, int s)
{
  __shared__ float Ua[16][68];
  __shared__ float Wa[16][68];
  const int tid = threadIdx.x, tx = tid & 15, ty = tid >> 4;
  const int p = blockIdx.z, b = 2 * p * s;
  const int i0 = blockIdx.y * 64, j0 = blockIdx.x * 64;
  const int sr = tid >> 4, sc = (tid & 15) * 4;
  float acc[4][4];
#pragma unroll
  for (int i = 0; i < 4; ++i)
#pragma unroll
    for (int j = 0; j < 4; ++j) acc[i][j] = 0.f;

  for (int k0 = 0; k0 < s; k0 += 16) {
    __syncthreads();
    {
      float4 u = *(const float4*)(S + (long)(b + k0 + sr) * CD + (b + s) + i0 + sc);
      *(float4*)&Ua[sr][sc] = u;
      float4 w = *(const float4*)(W + (long)(b + k0 + sr) * 2048 + b + j0 + sc);
      *(float4*)&Wa[sr][sc] = w;
    }
    __syncthreads();
#pragma unroll
    for (int kk = 0; kk < 16; ++kk) {
      float a[4], w2[4];
#pragma unroll
      for (int q = 0; q < 4; ++q) { a[q] = Ua[kk][ty * 4 + q]; w2[q] = Wa[kk][tx * 4 + q]; }
#pragma unroll
      for (int i = 0; i < 4; ++i)
#pragma unroll
        for (int j = 0; j < 4; ++j) acc[i][j] += a[i] * w2[j];
    }
  }
  float* Tp = T + (long)p * s * s;
#pragma unroll
  for (int i = 0; i < 4; ++i)
#pragma unroll
    for (int j = 0; j < 4; ++j)
      Tp[(long)(i0 + ty * 4 + i) * s + j0 + tx * 4 + j] = acc[i][j];
}

__global__ __launch_bounds__(256) void winv_nn(
    float* __restrict__ W, const float* __restrict__ T, int s)
{
  __shared__ float Wc[64][20];
  __shared__ float Tt[16][68];
  const int tid = threadIdx.x, tx = tid & 15, ty = tid >> 4;
  const int p = blockIdx.z, b = 2 * p * s, bs = b + s;
  const int i0 = blockIdx.y * 64, j0 = blockIdx.x * 64;
  const float* Tp = T + (long)p * s * s;
  float acc[4][4];
#pragma unroll
  for (int i = 0; i < 4; ++i)
#pragma unroll
    for (int j = 0; j < 4; ++j) acc[i][j] = 0.f;

  for (int k0 = 0; k0 < s; k0 += 16) {
    __syncthreads();
    {
      const int wr = tid >> 2, wc = (tid & 3) * 4;
      float4 a = *(const float4*)(W + (long)(bs + i0 + wr) * 2048 + bs + k0 + wc);
      *(float4*)&Wc[wr][wc] = a;
      const int tr = tid >> 4, tc = (tid & 15) * 4;
      float4 t2 = *(const float4*)(Tp + (long)(k0 + tr) * s + j0 + tc);
      *(float4*)&Tt[tr][tc] = t2;
    }
    __syncthreads();
#pragma unroll
    for (int kk = 0; kk < 16; ++kk) {
      float a[4], t3[4];
#pragma unroll
      for (int q = 0; q < 4; ++q) { a[q] = Wc[ty * 4 + q][kk]; t3[q] = Tt[kk][tx * 4 + q]; }
#pragma unroll
      for (int i = 0; i < 4; ++i)
#pragma unroll
        for (int j = 0; j < 4; ++j) acc[i][j] += a[i] * t3[j];
    }
  }
#pragma unroll
  for (int i = 0; i < 4; ++i)
#pragma unroll
    for (int j = 0; j < 4; ++j)
      W[(long)(bs + i0 + ty * 4 + i) * 2048 + b + j0 + tx * 4 + j] = -acc[i][j];
}

// ============================================================================
// Host launch.
// ws (80.1 MB): vec 128K | R1: SYM fp32 16M | R2 32M: Cp(2x16M)/SYMh transient,
//   then W fp32 @+1M, W_f16 @+17M, T @+25M, Kinv @+29M | R3: BIG f16 32M.
// d_out: Mt_h [0:32M), slotB [32M:64M) -> Xtr [0:32M) -> final Q fp32 (64M).
// ============================================================================
extern "C" void kernel_launch(void* const* d_in, const int* in_sizes, int n_in,
                              void* d_out, int out_size, void* d_ws, size_t ws_size,
                              hipStream_t stream)
{
  const float* s_in  = (const float*)d_in[0];
  const float* sgrad = (const float*)d_in[1];
  const float* L_h0  = (const float*)d_in[2];
  const float* L_c0  = (const float*)d_in[3];
  const float* R_h0  = (const float*)d_in[4];
  const float* R_c0  = (const float*)d_in[5];
  const float* L_bef = (const float*)d_in[6];
  const float* R_bef = (const float*)d_in[7];
  const float* Wih0  = (const float*)d_in[8];
  const float* Whh0  = (const float*)d_in[9];
  const float* bih0  = (const float*)d_in[10];
  const float* bhh0  = (const float*)d_in[11];
  const float* Wih1  = (const float*)d_in[12];
  const float* Whh1  = (const float*)d_in[13];
  const float* bih1  = (const float*)d_in[14];
  const float* bhh1  = (const float*)d_in[15];
  const float* L_W   = (const float*)d_in[16];
  const float* L_b   = (const float*)d_in[17];
  const float* R_W   = (const float*)d_in[18];
  const float* R_b   = (const float*)d_in[19];

  float* out = (float*)d_out;
  char*  ws  = (char*)d_ws;

  const size_t SYM_OFF = (size_t)1 << 17;
  const size_t OVL_OFF = SYM_OFF + ((size_t)16 << 20);
  const size_t BIG_OFF = OVL_OFF + ((size_t)32 << 20);
  float* vec  = (float*)ws;
  float* sums = vec;
  float* ggt  = vec + 4;
  float* gtg  = ggt + RD;
  float* lpre = gtg + CD;
  float* rpre = lpre + RD;
  float*     SYM  = (float*)(ws + SYM_OFF);
  float*     Cp   = (float*)(ws + OVL_OFF);
  _Float16*  SYMh = (_Float16*)(ws + OVL_OFF);
  float*     Wf   = (float*)(ws + OVL_OFF + ((size_t)1 << 20));    // inv(L), 16M
  _Float16*  Wh   = (_Float16*)(ws + OVL_OFF + ((size_t)17 << 20)); // 8M
  float*     Tbuf = (float*)(ws + OVL_OFF + ((size_t)25 << 20));   // 4M
  float*     Kinv = (float*)(ws + OVL_OFF + ((size_t)29 << 20));   // 16K
  _Float16*  BIG  = (_Float16*)(ws + BIG_OFF);                     // Gt->Pt->Xt->Qh

  _Float16* Mt_h  = (_Float16*)d_out;
  _Float16* slotB = Mt_h + (long)CD * RD;
  _Float16* Xtr   = (_Float16*)d_out;    // overwrites Mt_h (dead by then)

  hipMemsetAsync(vec, 0, (4 + RD) * sizeof(float), stream);

  const dim3 blk(256);
  const dim3 gK8(16, 16, 2);    // M=N=2048, K=8192, split-K 2
  const dim3 gK2(64, 16, 1);    // M=2048, N=8192, K=2048
  const dim3 gSym(32, 32);
  const int  castBlocks = (CD * RD / 4) / 256;

  cast_f16<<<castBlocks, blk, 0, stream>>>(s_in, Mt_h);
  cast_f16<<<castBlocks, blk, 0, stream>>>(sgrad, slotB);

  // Asym = 0.05 * sym(Mt * Sgt^T)
  gemm_nt_f16<<<gK8, blk, 0, stream>>>(Mt_h, slotB, Cp, nullptr, nullptr, nullptr,
                                       CD, CD, RD, 2, 0.f, 0.f, 1.f);
  sym_combine<<<gSym, blk, 0, stream>>>(Cp, SYM, CD, 2, 0.05f);
  cast_f16<<<(CD * CD / 4) / 256, blk, 0, stream>>>(SYM, SYMh);

  transpose_cast_f16<<<dim3(RD / 64, CD / 64), blk, 0, stream>>>(s_in, slotB); // Mtr

  // Gt = 0.1*Sgt - Asym*Mt
  gemm_nt_f16<<<gK2, blk, 0, stream>>>(SYMh, slotB, nullptr, BIG, sgrad, nullptr,
                                       CD, RD, CD, 1, 0.1f, 0.f, -1.f);

  row_sumsq<<<CD, blk, 0, stream>>>(BIG, gtg, 1.f / (float)RD);
  col_sumsq<<<dim3(RD / 256, CD / 256), blk, 0, stream>>>(BIG, ggt);

  lstm_head<<<RD / 256, blk, 0, stream>>>(ggt, RD, L_h0, L_c0, Wih0, Whh0, bih0, bhh0,
                                          Wih1, Whh1, bih1, bhh1, L_W, L_b, lpre, &sums[0]);
  lstm_head<<<CD / 256, blk, 0, stream>>>(gtg, CD, R_h0, R_c0, Wih0, Whh0, bih0, bhh0,
                                          Wih1, Whh1, bih1, bhh1, R_W, R_b, rpre, &sums[1]);

  scale_P<<<(CD * (RD / 4)) / 256, blk, 0, stream>>>(BIG, lpre, rpre, L_bef, R_bef, sums);

  // Bsym = 0.5 * sym(Mt * Pt^T)
  gemm_nt_f16<<<gK8, blk, 0, stream>>>(Mt_h, BIG, Cp, nullptr, nullptr, nullptr,
                                       CD, CD, RD, 2, 0.f, 0.f, 1.f);
  sym_combine<<<gSym, blk, 0, stream>>>(Cp, SYM, CD, 2, 0.5f);
  cast_f16<<<(CD * CD / 4) / 256, blk, 0, stream>>>(SYM, SYMh);

  // Xt = Mt - Pt + Bsym*Mt (in place)
  gemm_nt_f16<<<gK2, blk, 0, stream>>>(SYMh, slotB, nullptr, BIG, s_in, BIG,
                                       CD, RD, CD, 1, 1.f, -1.f, 1.f);

  // Gram S = 0.5 * sym(Xt * Xt^T)
  gemm_nt_f16<<<gK8, blk, 0, stream>>>(BIG, BIG, Cp, nullptr, nullptr, nullptr,
                                       CD, CD, RD, 2, 0.f, 0.f, 1.f);
  sym_combine<<<gSym, blk, 0, stream>>>(Cp, SYM, CD, 2, 0.5f);

  hipMemsetAsync(Wf, 0, (size_t)CD * CD * sizeof(float), stream);
  transpose_f16<<<dim3(RD / 64, CD / 64), blk, 0, stream>>>(BIG, Xtr);

  // Cholesky ladder (fused panel+trail), W diag seeds + Kinv per step
  for (int kb = 0; kb < 32; ++kb) {
    potrf64v2<<<1, blk, 0, stream>>>(SYM, Wf, Kinv, kb);
    const int nrem = 31 - kb;
    if (nrem > 0)
      ptstep<<<dim3(nrem, nrem + 1), blk, 0, stream>>>(SYM, Wf, Kinv, kb);
  }

  // W = inv(L) by doubling: 5 levels x 2 dispatches
  for (int lev = 0; lev < 5; ++lev) {
    const int s = 64 << lev, npairs = 16 >> lev;
    const dim3 g(s / 64, s / 64, npairs);
    winv_tn<<<g, blk, 0, stream>>>(SYM, Wf, Tbuf, s);
    winv_nn<<<g, blk, 0, stream>>>(Wf, Tbuf, s);
  }

  // Qh = W * Xt  (NT: A = W_f16 rows, B = Xtr rows), then upcast to d_out
  cast_f16<<<(CD * CD / 4) / 256, blk, 0, stream>>>(Wf, Wh);
  gemm_nt_f16<<<gK2, blk, 0, stream>>>(Wh, Xtr, nullptr, BIG, nullptr, nullptr,
                                       CD, RD, CD, 1, 0.f, 0.f, 1.f);
  cast_f32<<<(CD * RD / 8) / 256, blk, 0, stream>>>(BIG, out);
}